// Round 8
// baseline (761.638 us; speedup 1.0000x reference)
//
#include <hip/hip_runtime.h>
#include <hip/hip_fp16.h>
#include <math.h>

#define N_NODES  50000
#define N_EDGES  800000
#define IN_DIM   64
#define HID_DIM  64
#define N_CLS    10
#define ZROW     50000           // zero-row index for pad gathers
#define GRID     512             // blocks
#define NTHR     512             // threads/block (8 waves)
#define EPB      1563            // edges per block in P2: 512*1563 = 800256 >= 800000
#define PBSTRIDE 1568            // padded per-block packed region (ints)
#define NBUCK    196             // ceil(50000/256) coarse buckets (dst >> 8)
#define CSTRIDE  8192            // csr slots per bucket (max bucket ~4.4k + pads)
#define ECAP     6144            // LDS edge cache per bucket (max bucket ~4330)

// software grid barrier. Counters zeroed by hipMemsetAsync in kernel_launch
// (never rely on workspace initial contents -- re-poison). Co-residency:
// 512 blocks x 8 waves = 2 blocks/CU; capacity 4/CU (LDS 32.8KB, VGPR<=128).
__device__ __forceinline__ void gbar(int* cnt) {
    __threadfence();
    __syncthreads();
    if (threadIdx.x == 0) {
        __hip_atomic_fetch_add(cnt, 1, __ATOMIC_ACQ_REL, __HIP_MEMORY_SCOPE_AGENT);
        while (__hip_atomic_load(cnt, __ATOMIC_ACQUIRE, __HIP_MEMORY_SCOPE_AGENT) < GRID)
            __builtin_amdgcn_s_sleep(1);
    }
    __syncthreads();
}

// inclusive wave scan (64 lanes)
__device__ __forceinline__ int wscan_incl(int v, int lane) {
#pragma unroll
    for (int k = 1; k < 64; k <<= 1) {
        int u = __shfl_up(v, k, 64);
        if (lane >= k) v += u;
    }
    return v;
}

// unpack 8 fp16 (carried in a float4) and accumulate into two float4
__device__ __forceinline__ void h8_acc(float4 raw, float4& a, float4& b) {
    union { float4 f; __half2 h[4]; } u;
    u.f = raw;
    float2 p0 = __half22float2(u.h[0]);
    float2 p1 = __half22float2(u.h[1]);
    float2 p2 = __half22float2(u.h[2]);
    float2 p3 = __half22float2(u.h[3]);
    a.x += p0.x; a.y += p0.y; a.z += p1.x; a.w += p1.y;
    b.x += p2.x; b.y += p2.y; b.z += p3.x; b.w += p3.y;
}

__global__ __launch_bounds__(NTHR, 4) void mega(const float* __restrict__ x,
                                                const int* __restrict__ ei,
                                                const float* __restrict__ W1,
                                                const float* __restrict__ b1,
                                                const float* __restrict__ W2,
                                                const float* __restrict__ b2,
                                                float* __restrict__ out,
                                                int* __restrict__ ws) {
    // ---- workspace layout (ints), all segments 16B-aligned ----
    int*    bar     = ws;                        // 64 (memset to 0 at launch)
    int*    pk      = bar + 64;                  // 512*196 = 100352
    int*    off     = pk + GRID * NBUCK;         // 50176
    int*    nendA   = off + 50176;               // 50176
    float*  dinv    = (float*)(nendA + 50176);   // 50176
    int*    packedB = (int*)(dinv + 50176);      // 512*1568 = 802816 (3.2 MB)
    int*    csr     = packedB + GRID * PBSTRIDE; // 196*8192 = 1605632 (6.4 MB)
    float2* xlh     = (float2*)(csr + NBUCK * CSTRIDE);              // (N+1) x 16 float2
    __half2* hlh2   = (__half2*)(xlh + (size_t)(N_NODES + 1) * 16);  // (N+1) x 8 half2

    const int* srcA = ei;                 // edge_index[0]
    const int* dstA = ei + N_EDGES;       // edge_index[1]

    int t = threadIdx.x;
    int b = blockIdx.x;
    int lane = t & 63, w = t >> 6;

    __shared__ __align__(16) int smem[8208];   // 32832 B union (max = P3)

    // ================= P2: block-local counting sort by coarse bucket ===============
    // Zero global atomics; packed stream-out coalesced; pk[(block,bucket)] descriptor.
    {
        int* hist   = smem;          // 256
        int* curL   = smem + 256;    // 256
        int* wpart  = smem + 512;    // 8
        int* dcache = smem + 520;    // 1563
        int* sstage = smem + 2083;   // 1563
        if (t < 256) hist[t] = 0;
        if (b == 0) {                 // zero pad rows (consumed after later barriers)
            if (t < 16) xlh[(size_t)ZROW * 16 + t] = make_float2(0.f, 0.f);
            if (t >= 16 && t < 24) hlh2[(size_t)ZROW * 8 + (t - 16)] = __floats2half2_rn(0.f, 0.f);
        }
        __syncthreads();
        int beg = b * EPB;
        int n = N_EDGES - beg; if (n > EPB) n = EPB;
        for (int i = t; i < n; i += NTHR) {
            int d = dstA[beg + i];
            dcache[i] = d;
            atomicAdd(&hist[d >> 8], 1);                  // LDS atomic
        }
        __syncthreads();
        int hv = 0, incl = 0;
        if (t < 256) {
            hv = hist[t];
            incl = wscan_incl(hv, lane);
            if (lane == 63) wpart[w] = incl;              // w in 0..3
        }
        __syncthreads();
        if (t < 64) { int p = (t < 4) ? wpart[t] : 0; int pi = wscan_incl(p, t); if (t < 4) wpart[t] = pi; }
        __syncthreads();
        if (t < 256) {
            int base = incl - hv + ((w > 0) ? wpart[w - 1] : 0);   // exclusive
            curL[t] = base;
            if (t < NBUCK) pk[b * NBUCK + t] = (base << 16) | hv;
        }
        __syncthreads();
        for (int i = t; i < n; i += NTHR) {
            int d = dcache[i];
            int sv = srcA[beg + i];
            int slot = atomicAdd(&curL[d >> 8], 1);       // LDS atomic
            sstage[slot] = ((d & 255) << 16) | sv;
        }
        __syncthreads();
        int obase = b * PBSTRIDE;
        for (int i = t; i < n; i += NTHR)                 // coalesced stream-out
            packedB[obase + i] = sstage[i];
    }
    gbar(&bar[0]);

    // ================= P3: per-bucket CSR + off/nend/dinv (196 blocks) ==============
    if (b < NBUCK) {
        int* sA     = smem;          // 512 seg begin (abs packedB index)
        int* sB     = smem + 512;    // 512 seg len
        int* sC     = smem + 1024;   // 512 seg offset in ecache
        int* hist   = smem + 1536;   // 256 per-node counts
        int* nsc    = smem + 1792;   // 256 per-node csr cursor
        int* wpart  = smem + 2048;   // 8
        int* ecache = smem + 2064;   // 6144 (ends at 8208)
        int bucket = b;
        if (t < 256) hist[t] = 0;
        {   // descriptors: one segment per thread (NSEG == NTHR == 512)
            int pkv = pk[t * NBUCK + bucket];
            sA[t] = t * PBSTRIDE + (pkv >> 16);
            sB[t] = pkv & 0xFFFF;
        }
        __syncthreads();
        // 512-entry exclusive scan of segment lengths -> ecache offsets
        int sl = sB[t];
        int incl = wscan_incl(sl, lane);
        if (lane == 63) wpart[w] = incl;                  // w in 0..7
        __syncthreads();
        if (t < 64) { int p = (t < 8) ? wpart[t] : 0; int pi = wscan_incl(p, t); if (t < 8) wpart[t] = pi; }
        __syncthreads();
        int so_ = incl - sl + ((w > 0) ? wpart[w - 1] : 0);
        sC[t] = so_;
        __syncthreads();
        int ne = sC[511] + sB[511];
        // ingest: thread t streams its segment into ecache + node histogram
        {
            int sb = sA[t], so = sC[t], ln = sB[t];
            for (int i = 0; i < ln; ++i) {
                int p = packedB[sb + i];
                ecache[so + i] = p;
                atomicAdd(&hist[p >> 16], 1);             // LDS atomic
            }
        }
        __syncthreads();
        // per-node padded scan -> csr offsets, off/nend/dinv
        int hv = 0, incl2 = 0, padded = 0;
        if (t < 256) {
            hv = hist[t];
            padded = (hv + 3) & ~3;
            incl2 = wscan_incl(padded, lane);
            if (lane == 63) wpart[w] = incl2;
        }
        __syncthreads();
        if (t < 64) { int p = (t < 4) ? wpart[t] : 0; int pi = wscan_incl(p, t); if (t < 4) wpart[t] = pi; }
        __syncthreads();
        int myend = 0;
        if (t < 256) {
            int o = bucket * CSTRIDE + incl2 - padded + ((w > 0) ? wpart[w - 1] : 0);
            nsc[t] = o;
            myend = o + padded;
            int node = bucket * 256 + t;
            if (node < N_NODES) {
                off[node]   = o;
                nendA[node] = myend;
                dinv[node]  = rsqrtf((float)(hv + 1));    // +1 self-loop
            }
        }
        __syncthreads();
        // csr scatter via LDS cursor
        for (int i = t; i < ne; i += NTHR) {
            int p = ecache[i];
            int slot = atomicAdd(&nsc[p >> 16], 1);       // LDS atomic
            csr[slot] = p & 0xFFFF;
        }
        __syncthreads();
        if (t < 256) {
            for (int i = nsc[t]; i < myend; ++i) csr[i] = ZROW;   // <=3 pads/node
        }
    }
    gbar(&bar[1]);

    // ================= P4: xl' = fp16((x @ W1) * dinv), 32-row tiles ================
    {
        float4* sW4 = (float4*)smem;                 // 1024 f4 = 16 KB
        float4* sx4 = (float4*)(smem + 4096);        // 512 f4 = 8 KB
        const float4* W4 = (const float4*)W1;
        sW4[t]       = W4[t];
        sW4[t + 512] = W4[t + 512];
        const float4* x4 = (const float4*)x;
        int r = t >> 4, cq = t & 15;
        for (int vb = b; vb < 1563; vb += GRID) {    // 1563*32 = 50016 rows
            __syncthreads();                         // sW4 ready / sx4 WAR
            int row0 = vb * 32 + r;
            sx4[t] = (row0 < N_NODES) ? x4[(size_t)row0 * 16 + cq]
                                      : make_float4(0.f, 0.f, 0.f, 0.f);
            __syncthreads();
            const float4* sxr = &sx4[r * 16];
            float ax = 0.f, ay = 0.f, az = 0.f, aw = 0.f;
#pragma unroll
            for (int k4 = 0; k4 < 16; ++k4) {
                float4 xv = sxr[k4];
                float4 w0 = sW4[(k4 * 4 + 0) * 16 + cq];
                float4 w1 = sW4[(k4 * 4 + 1) * 16 + cq];
                float4 w2 = sW4[(k4 * 4 + 2) * 16 + cq];
                float4 w3 = sW4[(k4 * 4 + 3) * 16 + cq];
                ax += xv.x * w0.x + xv.y * w1.x + xv.z * w2.x + xv.w * w3.x;
                ay += xv.x * w0.y + xv.y * w1.y + xv.z * w2.y + xv.w * w3.y;
                az += xv.x * w0.z + xv.y * w1.z + xv.z * w2.z + xv.w * w3.z;
                aw += xv.x * w0.w + xv.y * w1.w + xv.z * w2.w + xv.w * w3.w;
            }
            if (row0 < N_NODES) {
                float dvv = dinv[row0];
                union { __half2 h[2]; float2 f; } u;
                u.h[0] = __floats2half2_rn(ax * dvv, ay * dvv);
                u.h[1] = __floats2half2_rn(az * dvv, aw * dvv);
                xlh[(size_t)row0 * 16 + cq] = u.f;
            }
        }
    }
    gbar(&bar[2]);

    // ================= P5: layer-1 gather + relu + (h@W2)*dinv -> fp16 hl' ==========
    {
        float* sW2 = (float*)smem;                   // [64][11] padded
        for (int i = t; i < HID_DIM * N_CLS; i += NTHR) {
            int rr = i / N_CLS, cc = i - rr * N_CLS;
            sW2[rr * (N_CLS + 1) + cc] = W2[i];
        }
        __syncthreads();
        const float4* xlph = (const float4*)xlh;
        int d8 = t & 7;
        for (int vb = b; vb < 784; vb += GRID) {     // 784*64 = 50176
            int node = vb * 64 + (t >> 3);
            bool valid = node < N_NODES;
            int nd = valid ? node : ZROW;
            int beg = 0, end = 0;
            if (valid) { beg = off[node]; end = nendA[node]; }
            float4 aA = make_float4(0.f, 0.f, 0.f, 0.f);
            float4 aB = make_float4(0.f, 0.f, 0.f, 0.f);
            h8_acc(xlph[(size_t)nd * 8 + d8], aA, aB);   // self-loop
            int j = beg;
            for (; j + 8 <= end; j += 8) {
                int4 c0 = *(const int4*)(csr + j);
                int4 c1 = *(const int4*)(csr + j + 4);
                float4 r0 = xlph[(size_t)c0.x * 8 + d8];
                float4 r1 = xlph[(size_t)c0.y * 8 + d8];
                float4 r2 = xlph[(size_t)c0.z * 8 + d8];
                float4 r3 = xlph[(size_t)c0.w * 8 + d8];
                float4 r4 = xlph[(size_t)c1.x * 8 + d8];
                float4 r5 = xlph[(size_t)c1.y * 8 + d8];
                float4 r6 = xlph[(size_t)c1.z * 8 + d8];
                float4 r7 = xlph[(size_t)c1.w * 8 + d8];
                h8_acc(r0, aA, aB); h8_acc(r1, aA, aB);
                h8_acc(r2, aA, aB); h8_acc(r3, aA, aB);
                h8_acc(r4, aA, aB); h8_acc(r5, aA, aB);
                h8_acc(r6, aA, aB); h8_acc(r7, aA, aB);
            }
            if (j < end) {                           // one padded 4-block
                int4 c0 = *(const int4*)(csr + j);
                float4 r0 = xlph[(size_t)c0.x * 8 + d8];
                float4 r1 = xlph[(size_t)c0.y * 8 + d8];
                float4 r2 = xlph[(size_t)c0.z * 8 + d8];
                float4 r3 = xlph[(size_t)c0.w * 8 + d8];
                h8_acc(r0, aA, aB); h8_acc(r1, aA, aB);
                h8_acc(r2, aA, aB); h8_acc(r3, aA, aB);
            }
            float dvv = valid ? dinv[node] : 0.0f;
            float4 b1a = ((const float4*)b1)[d8 * 2];
            float4 b1b = ((const float4*)b1)[d8 * 2 + 1];
            float h0 = fmaxf(dvv * aA.x + b1a.x, 0.0f);
            float h1 = fmaxf(dvv * aA.y + b1a.y, 0.0f);
            float h2 = fmaxf(dvv * aA.z + b1a.z, 0.0f);
            float h3 = fmaxf(dvv * aA.w + b1a.w, 0.0f);
            float h4 = fmaxf(dvv * aB.x + b1b.x, 0.0f);
            float h5 = fmaxf(dvv * aB.y + b1b.y, 0.0f);
            float h6 = fmaxf(dvv * aB.z + b1b.z, 0.0f);
            float h7 = fmaxf(dvv * aB.w + b1b.w, 0.0f);
            float p[N_CLS];
            int k0 = d8 * 8;
#pragma unroll
            for (int c = 0; c < N_CLS; ++c)
                p[c] = h0 * sW2[(k0 + 0) * (N_CLS + 1) + c] + h1 * sW2[(k0 + 1) * (N_CLS + 1) + c]
                     + h2 * sW2[(k0 + 2) * (N_CLS + 1) + c] + h3 * sW2[(k0 + 3) * (N_CLS + 1) + c]
                     + h4 * sW2[(k0 + 4) * (N_CLS + 1) + c] + h5 * sW2[(k0 + 5) * (N_CLS + 1) + c]
                     + h6 * sW2[(k0 + 6) * (N_CLS + 1) + c] + h7 * sW2[(k0 + 7) * (N_CLS + 1) + c];
#pragma unroll
            for (int k = 1; k < 8; k <<= 1) {
#pragma unroll
                for (int c = 0; c < N_CLS; ++c) p[c] += __shfl_xor(p[c], k, 64);
            }
            if (valid) {
                float va = 0.f, vb2 = 0.f;
                int c0i = d8 * 2, c1i = d8 * 2 + 1;
#pragma unroll
                for (int c = 0; c < N_CLS; ++c) {
                    va  = (c0i == c) ? p[c] : va;
                    vb2 = (c1i == c) ? p[c] : vb2;
                }
                hlh2[(size_t)node * 8 + d8] = __floats2half2_rn(va * dvv, vb2 * dvv);
            }
        }
    }
    gbar(&bar[3]);

    // ================= P6: layer-2 gather + b2 + log_softmax ========================
    {
        float2* out2 = (float2*)out;
        int d8 = t & 7;
        for (int vb = b; vb < 784; vb += GRID) {
            int node = vb * 64 + (t >> 3);
            bool valid = node < N_NODES;
            int nd = valid ? node : ZROW;
            int beg = 0, end = 0;
            if (valid) { beg = off[node]; end = nendA[node]; }
            float2 self = __half22float2(hlh2[(size_t)nd * 8 + d8]);
            float accx = self.x, accy = self.y;
            int j = beg;
            for (; j + 8 <= end; j += 8) {
                int4 c0 = *(const int4*)(csr + j);
                int4 c1 = *(const int4*)(csr + j + 4);
                float2 f0 = __half22float2(hlh2[(size_t)c0.x * 8 + d8]);
                float2 f1 = __half22float2(hlh2[(size_t)c0.y * 8 + d8]);
                float2 f2 = __half22float2(hlh2[(size_t)c0.z * 8 + d8]);
                float2 f3 = __half22float2(hlh2[(size_t)c0.w * 8 + d8]);
                float2 f4 = __half22float2(hlh2[(size_t)c1.x * 8 + d8]);
                float2 f5 = __half22float2(hlh2[(size_t)c1.y * 8 + d8]);
                float2 f6 = __half22float2(hlh2[(size_t)c1.z * 8 + d8]);
                float2 f7 = __half22float2(hlh2[(size_t)c1.w * 8 + d8]);
                accx += ((f0.x + f1.x) + (f2.x + f3.x)) + ((f4.x + f5.x) + (f6.x + f7.x));
                accy += ((f0.y + f1.y) + (f2.y + f3.y)) + ((f4.y + f5.y) + (f6.y + f7.y));
            }
            if (j < end) {
                int4 c0 = *(const int4*)(csr + j);
                float2 f0 = __half22float2(hlh2[(size_t)c0.x * 8 + d8]);
                float2 f1 = __half22float2(hlh2[(size_t)c0.y * 8 + d8]);
                float2 f2 = __half22float2(hlh2[(size_t)c0.z * 8 + d8]);
                float2 f3 = __half22float2(hlh2[(size_t)c0.w * 8 + d8]);
                accx += (f0.x + f1.x) + (f2.x + f3.x);
                accy += (f0.y + f1.y) + (f2.y + f3.y);
            }
            bool act = valid && (d8 < 5);
            float dvv = valid ? dinv[node] : 0.f;
            float2 bb = make_float2(0.f, 0.f);
            if (d8 < 5) bb = ((const float2*)b2)[d8];
            float vx = act ? dvv * accx + bb.x : -INFINITY;
            float vy = act ? dvv * accy + bb.y : -INFINITY;
            float m = fmaxf(vx, vy);
#pragma unroll
            for (int k = 1; k < 8; k <<= 1) m = fmaxf(m, __shfl_xor(m, k, 64));
            float ex = act ? (expf(vx - m) + expf(vy - m)) : 0.f;
#pragma unroll
            for (int k = 1; k < 8; k <<= 1) ex += __shfl_xor(ex, k, 64);
            if (act) {
                float l = m + logf(ex);
                out2[(size_t)node * 5 + d8] = make_float2(vx - l, vy - l);
            }
        }
    }
}

extern "C" void kernel_launch(void* const* d_in, const int* in_sizes, int n_in,
                              void* d_out, int out_size, void* d_ws, size_t ws_size,
                              hipStream_t stream) {
    const float* x  = (const float*)d_in[0];
    const int*   ei = (const int*)d_in[1];
    const float* W1 = (const float*)d_in[2];
    const float* b1 = (const float*)d_in[3];
    const float* W2 = (const float*)d_in[4];
    const float* b2 = (const float*)d_in[5];
    float* out = (float*)d_out;
    int*   ws  = (int*)d_ws;

    // Zero the grid-barrier counters -- stream-ordered, replayed in the captured
    // graph each iteration. Never rely on workspace initial contents (re-poison).
    hipMemsetAsync(d_ws, 0, 256, stream);
    mega<<<GRID, NTHR, 0, stream>>>(x, ei, W1, b1, W2, b2, out, ws);
    (void)in_sizes; (void)n_in; (void)out_size; (void)ws_size;
}

// Round 9
// 410.656 us; speedup vs baseline: 1.8547x; 1.8547x over previous
//
#include <hip/hip_runtime.h>
#include <hip/hip_fp16.h>
#include <math.h>

#define N_NODES  50000
#define N_EDGES  800000
#define IN_DIM   64
#define HID_DIM  64
#define N_CLS    10
#define ZROW     50000           // zero-row index for pad gathers
#define GRID     512             // blocks
#define NTHR     512             // threads/block (8 waves)
#define EPB      1563            // edges per block in P2: 512*1563 = 800256 >= 800000
#define PBSTRIDE 1568            // padded per-block packed region (ints)
#define NBUCK    196             // ceil(50000/256) coarse buckets (dst >> 8)
#define CSTRIDE  8192            // csr slots per bucket (max bucket ~4.4k + pads)
#define ECAP     6144            // LDS edge cache per bucket (max bucket ~4330)

// software grid barrier. KEY: spin on a RELAXED load (no per-poll L2 invalidate --
// an AGENT-scope ACQUIRE in the spin loop invalidates the whole XCD L2 every poll,
// which destroyed all cache locality in R7/R8: 178 GB/s, VALU 2%, 700 us).
// One acquire fence AFTER the spin gives the needed cross-XCD visibility.
// Counters zeroed by hipMemsetAsync in kernel_launch (never trust ws re-poison).
// Co-residency: 512 blocks x 8 waves = 2 blocks/CU; capacity 4/CU.
__device__ __forceinline__ void gbar(int* cnt) {
    __syncthreads();
    if (threadIdx.x == 0) {
        __hip_atomic_fetch_add(cnt, 1, __ATOMIC_RELEASE, __HIP_MEMORY_SCOPE_AGENT);
        while (__hip_atomic_load(cnt, __ATOMIC_RELAXED, __HIP_MEMORY_SCOPE_AGENT) < GRID)
            __builtin_amdgcn_s_sleep(2);
    }
    __syncthreads();
    __builtin_amdgcn_fence(__ATOMIC_ACQUIRE, "agent");   // single L1/L2 inv per wave
}

// inclusive wave scan (64 lanes)
__device__ __forceinline__ int wscan_incl(int v, int lane) {
#pragma unroll
    for (int k = 1; k < 64; k <<= 1) {
        int u = __shfl_up(v, k, 64);
        if (lane >= k) v += u;
    }
    return v;
}

// unpack 8 fp16 (carried in a float4) and accumulate into two float4
__device__ __forceinline__ void h8_acc(float4 raw, float4& a, float4& b) {
    union { float4 f; __half2 h[4]; } u;
    u.f = raw;
    float2 p0 = __half22float2(u.h[0]);
    float2 p1 = __half22float2(u.h[1]);
    float2 p2 = __half22float2(u.h[2]);
    float2 p3 = __half22float2(u.h[3]);
    a.x += p0.x; a.y += p0.y; a.z += p1.x; a.w += p1.y;
    b.x += p2.x; b.y += p2.y; b.z += p3.x; b.w += p3.y;
}

__global__ __launch_bounds__(NTHR, 4) void mega(const float* __restrict__ x,
                                                const int* __restrict__ ei,
                                                const float* __restrict__ W1,
                                                const float* __restrict__ b1,
                                                const float* __restrict__ W2,
                                                const float* __restrict__ b2,
                                                float* __restrict__ out,
                                                int* __restrict__ ws) {
    // ---- workspace layout (ints), all segments 16B-aligned ----
    int*    bar     = ws;                        // 64 (memset to 0 at launch)
    int*    pk      = bar + 64;                  // 512*196 = 100352
    int*    off     = pk + GRID * NBUCK;         // 50176
    int*    nendA   = off + 50176;               // 50176
    float*  dinv    = (float*)(nendA + 50176);   // 50176
    int*    packedB = (int*)(dinv + 50176);      // 512*1568 = 802816 (3.2 MB)
    int*    csr     = packedB + GRID * PBSTRIDE; // 196*8192 = 1605632 (6.4 MB)
    float2* xlh     = (float2*)(csr + NBUCK * CSTRIDE);              // (N+1) x 16 float2
    __half2* hlh2   = (__half2*)(xlh + (size_t)(N_NODES + 1) * 16);  // (N+1) x 8 half2

    const int* srcA = ei;                 // edge_index[0]
    const int* dstA = ei + N_EDGES;       // edge_index[1]

    int t = threadIdx.x;
    int b = blockIdx.x;
    int lane = t & 63, w = t >> 6;

    __shared__ __align__(16) int smem[8208];   // 32832 B union (max = P3)

    // ================= P2: block-local counting sort by coarse bucket ===============
    // Zero global atomics; packed stream-out coalesced; pk[(block,bucket)] descriptor.
    {
        int* hist   = smem;          // 256
        int* curL   = smem + 256;    // 256
        int* wpart  = smem + 512;    // 8
        int* dcache = smem + 520;    // 1563
        int* sstage = smem + 2083;   // 1563
        if (t < 256) hist[t] = 0;
        if (b == 0) {                 // zero pad rows (consumed after later barriers)
            if (t < 16) xlh[(size_t)ZROW * 16 + t] = make_float2(0.f, 0.f);
            if (t >= 16 && t < 24) hlh2[(size_t)ZROW * 8 + (t - 16)] = __floats2half2_rn(0.f, 0.f);
        }
        __syncthreads();
        int beg = b * EPB;
        int n = N_EDGES - beg; if (n > EPB) n = EPB;
        for (int i = t; i < n; i += NTHR) {
            int d = dstA[beg + i];
            dcache[i] = d;
            atomicAdd(&hist[d >> 8], 1);                  // LDS atomic
        }
        __syncthreads();
        int hv = 0, incl = 0;
        if (t < 256) {
            hv = hist[t];
            incl = wscan_incl(hv, lane);
            if (lane == 63) wpart[w] = incl;              // w in 0..3
        }
        __syncthreads();
        if (t < 64) { int p = (t < 4) ? wpart[t] : 0; int pi = wscan_incl(p, t); if (t < 4) wpart[t] = pi; }
        __syncthreads();
        if (t < 256) {
            int base = incl - hv + ((w > 0) ? wpart[w - 1] : 0);   // exclusive
            curL[t] = base;
            if (t < NBUCK) pk[b * NBUCK + t] = (base << 16) | hv;
        }
        __syncthreads();
        for (int i = t; i < n; i += NTHR) {
            int d = dcache[i];
            int sv = srcA[beg + i];
            int slot = atomicAdd(&curL[d >> 8], 1);       // LDS atomic
            sstage[slot] = ((d & 255) << 16) | sv;
        }
        __syncthreads();
        int obase = b * PBSTRIDE;
        for (int i = t; i < n; i += NTHR)                 // coalesced stream-out
            packedB[obase + i] = sstage[i];
    }
    gbar(&bar[0]);

    // ================= P3: per-bucket CSR + off/nend/dinv (196 blocks) ==============
    if (b < NBUCK) {
        int* sA     = smem;          // 512 seg begin (abs packedB index)
        int* sB     = smem + 512;    // 512 seg len
        int* sC     = smem + 1024;   // 512 seg offset in ecache
        int* hist   = smem + 1536;   // 256 per-node counts
        int* nsc    = smem + 1792;   // 256 per-node csr cursor
        int* wpart  = smem + 2048;   // 8
        int* ecache = smem + 2064;   // 6144 (ends at 8208)
        int bucket = b;
        if (t < 256) hist[t] = 0;
        {   // descriptors: one segment per thread (NSEG == NTHR == 512)
            int pkv = pk[t * NBUCK + bucket];
            sA[t] = t * PBSTRIDE + (pkv >> 16);
            sB[t] = pkv & 0xFFFF;
        }
        __syncthreads();
        // 512-entry exclusive scan of segment lengths -> ecache offsets
        int sl = sB[t];
        int incl = wscan_incl(sl, lane);
        if (lane == 63) wpart[w] = incl;                  // w in 0..7
        __syncthreads();
        if (t < 64) { int p = (t < 8) ? wpart[t] : 0; int pi = wscan_incl(p, t); if (t < 8) wpart[t] = pi; }
        __syncthreads();
        int so_ = incl - sl + ((w > 0) ? wpart[w - 1] : 0);
        sC[t] = so_;
        __syncthreads();
        int ne = sC[511] + sB[511];
        // ingest: thread t streams its segment into ecache + node histogram
        {
            int sb = sA[t], so = sC[t], ln = sB[t];
            for (int i = 0; i < ln; ++i) {
                int p = packedB[sb + i];
                ecache[so + i] = p;
                atomicAdd(&hist[p >> 16], 1);             // LDS atomic
            }
        }
        __syncthreads();
        // per-node padded scan -> csr offsets, off/nend/dinv
        int hv = 0, incl2 = 0, padded = 0;
        if (t < 256) {
            hv = hist[t];
            padded = (hv + 3) & ~3;
            incl2 = wscan_incl(padded, lane);
            if (lane == 63) wpart[w] = incl2;
        }
        __syncthreads();
        if (t < 64) { int p = (t < 4) ? wpart[t] : 0; int pi = wscan_incl(p, t); if (t < 4) wpart[t] = pi; }
        __syncthreads();
        int myend = 0;
        if (t < 256) {
            int o = bucket * CSTRIDE + incl2 - padded + ((w > 0) ? wpart[w - 1] : 0);
            nsc[t] = o;
            myend = o + padded;
            int node = bucket * 256 + t;
            if (node < N_NODES) {
                off[node]   = o;
                nendA[node] = myend;
                dinv[node]  = rsqrtf((float)(hv + 1));    // +1 self-loop
            }
        }
        __syncthreads();
        // csr scatter via LDS cursor
        for (int i = t; i < ne; i += NTHR) {
            int p = ecache[i];
            int slot = atomicAdd(&nsc[p >> 16], 1);       // LDS atomic
            csr[slot] = p & 0xFFFF;
        }
        __syncthreads();
        if (t < 256) {
            for (int i = nsc[t]; i < myend; ++i) csr[i] = ZROW;   // <=3 pads/node
        }
    }
    gbar(&bar[1]);

    // ================= P4: xl' = fp16((x @ W1) * dinv), 32-row tiles ================
    {
        float4* sW4 = (float4*)smem;                 // 1024 f4 = 16 KB
        float4* sx4 = (float4*)(smem + 4096);        // 512 f4 = 8 KB
        const float4* W4 = (const float4*)W1;
        sW4[t]       = W4[t];
        sW4[t + 512] = W4[t + 512];
        const float4* x4 = (const float4*)x;
        int r = t >> 4, cq = t & 15;
        for (int vb = b; vb < 1563; vb += GRID) {    // 1563*32 = 50016 rows
            __syncthreads();                         // sW4 ready / sx4 WAR
            int row0 = vb * 32 + r;
            sx4[t] = (row0 < N_NODES) ? x4[(size_t)row0 * 16 + cq]
                                      : make_float4(0.f, 0.f, 0.f, 0.f);
            __syncthreads();
            const float4* sxr = &sx4[r * 16];
            float ax = 0.f, ay = 0.f, az = 0.f, aw = 0.f;
#pragma unroll
            for (int k4 = 0; k4 < 16; ++k4) {
                float4 xv = sxr[k4];
                float4 w0 = sW4[(k4 * 4 + 0) * 16 + cq];
                float4 w1 = sW4[(k4 * 4 + 1) * 16 + cq];
                float4 w2 = sW4[(k4 * 4 + 2) * 16 + cq];
                float4 w3 = sW4[(k4 * 4 + 3) * 16 + cq];
                ax += xv.x * w0.x + xv.y * w1.x + xv.z * w2.x + xv.w * w3.x;
                ay += xv.x * w0.y + xv.y * w1.y + xv.z * w2.y + xv.w * w3.y;
                az += xv.x * w0.z + xv.y * w1.z + xv.z * w2.z + xv.w * w3.z;
                aw += xv.x * w0.w + xv.y * w1.w + xv.z * w2.w + xv.w * w3.w;
            }
            if (row0 < N_NODES) {
                float dvv = dinv[row0];
                union { __half2 h[2]; float2 f; } u;
                u.h[0] = __floats2half2_rn(ax * dvv, ay * dvv);
                u.h[1] = __floats2half2_rn(az * dvv, aw * dvv);
                xlh[(size_t)row0 * 16 + cq] = u.f;
            }
        }
    }
    gbar(&bar[2]);

    // ================= P5: layer-1 gather + relu + (h@W2)*dinv -> fp16 hl' ==========
    {
        float* sW2 = (float*)smem;                   // [64][11] padded
        for (int i = t; i < HID_DIM * N_CLS; i += NTHR) {
            int rr = i / N_CLS, cc = i - rr * N_CLS;
            sW2[rr * (N_CLS + 1) + cc] = W2[i];
        }
        __syncthreads();
        const float4* xlph = (const float4*)xlh;
        int d8 = t & 7;
        for (int vb = b; vb < 784; vb += GRID) {     // 784*64 = 50176
            int node = vb * 64 + (t >> 3);
            bool valid = node < N_NODES;
            int nd = valid ? node : ZROW;
            int beg = 0, end = 0;
            if (valid) { beg = off[node]; end = nendA[node]; }
            float4 aA = make_float4(0.f, 0.f, 0.f, 0.f);
            float4 aB = make_float4(0.f, 0.f, 0.f, 0.f);
            h8_acc(xlph[(size_t)nd * 8 + d8], aA, aB);   // self-loop
            int j = beg;
            for (; j + 8 <= end; j += 8) {
                int4 c0 = *(const int4*)(csr + j);
                int4 c1 = *(const int4*)(csr + j + 4);
                float4 r0 = xlph[(size_t)c0.x * 8 + d8];
                float4 r1 = xlph[(size_t)c0.y * 8 + d8];
                float4 r2 = xlph[(size_t)c0.z * 8 + d8];
                float4 r3 = xlph[(size_t)c0.w * 8 + d8];
                float4 r4 = xlph[(size_t)c1.x * 8 + d8];
                float4 r5 = xlph[(size_t)c1.y * 8 + d8];
                float4 r6 = xlph[(size_t)c1.z * 8 + d8];
                float4 r7 = xlph[(size_t)c1.w * 8 + d8];
                h8_acc(r0, aA, aB); h8_acc(r1, aA, aB);
                h8_acc(r2, aA, aB); h8_acc(r3, aA, aB);
                h8_acc(r4, aA, aB); h8_acc(r5, aA, aB);
                h8_acc(r6, aA, aB); h8_acc(r7, aA, aB);
            }
            if (j < end) {                           // one padded 4-block
                int4 c0 = *(const int4*)(csr + j);
                float4 r0 = xlph[(size_t)c0.x * 8 + d8];
                float4 r1 = xlph[(size_t)c0.y * 8 + d8];
                float4 r2 = xlph[(size_t)c0.z * 8 + d8];
                float4 r3 = xlph[(size_t)c0.w * 8 + d8];
                h8_acc(r0, aA, aB); h8_acc(r1, aA, aB);
                h8_acc(r2, aA, aB); h8_acc(r3, aA, aB);
            }
            float dvv = valid ? dinv[node] : 0.0f;
            float4 b1a = ((const float4*)b1)[d8 * 2];
            float4 b1b = ((const float4*)b1)[d8 * 2 + 1];
            float h0 = fmaxf(dvv * aA.x + b1a.x, 0.0f);
            float h1 = fmaxf(dvv * aA.y + b1a.y, 0.0f);
            float h2 = fmaxf(dvv * aA.z + b1a.z, 0.0f);
            float h3 = fmaxf(dvv * aA.w + b1a.w, 0.0f);
            float h4 = fmaxf(dvv * aB.x + b1b.x, 0.0f);
            float h5 = fmaxf(dvv * aB.y + b1b.y, 0.0f);
            float h6 = fmaxf(dvv * aB.z + b1b.z, 0.0f);
            float h7 = fmaxf(dvv * aB.w + b1b.w, 0.0f);
            float p[N_CLS];
            int k0 = d8 * 8;
#pragma unroll
            for (int c = 0; c < N_CLS; ++c)
                p[c] = h0 * sW2[(k0 + 0) * (N_CLS + 1) + c] + h1 * sW2[(k0 + 1) * (N_CLS + 1) + c]
                     + h2 * sW2[(k0 + 2) * (N_CLS + 1) + c] + h3 * sW2[(k0 + 3) * (N_CLS + 1) + c]
                     + h4 * sW2[(k0 + 4) * (N_CLS + 1) + c] + h5 * sW2[(k0 + 5) * (N_CLS + 1) + c]
                     + h6 * sW2[(k0 + 6) * (N_CLS + 1) + c] + h7 * sW2[(k0 + 7) * (N_CLS + 1) + c];
#pragma unroll
            for (int k = 1; k < 8; k <<= 1) {
#pragma unroll
                for (int c = 0; c < N_CLS; ++c) p[c] += __shfl_xor(p[c], k, 64);
            }
            if (valid) {
                float va = 0.f, vb2 = 0.f;
                int c0i = d8 * 2, c1i = d8 * 2 + 1;
#pragma unroll
                for (int c = 0; c < N_CLS; ++c) {
                    va  = (c0i == c) ? p[c] : va;
                    vb2 = (c1i == c) ? p[c] : vb2;
                }
                hlh2[(size_t)node * 8 + d8] = __floats2half2_rn(va * dvv, vb2 * dvv);
            }
        }
    }
    gbar(&bar[2 + 1]);

    // ================= P6: layer-2 gather + b2 + log_softmax ========================
    {
        float2* out2 = (float2*)out;
        int d8 = t & 7;
        for (int vb = b; vb < 784; vb += GRID) {
            int node = vb * 64 + (t >> 3);
            bool valid = node < N_NODES;
            int nd = valid ? node : ZROW;
            int beg = 0, end = 0;
            if (valid) { beg = off[node]; end = nendA[node]; }
            float2 self = __half22float2(hlh2[(size_t)nd * 8 + d8]);
            float accx = self.x, accy = self.y;
            int j = beg;
            for (; j + 8 <= end; j += 8) {
                int4 c0 = *(const int4*)(csr + j);
                int4 c1 = *(const int4*)(csr + j + 4);
                float2 f0 = __half22float2(hlh2[(size_t)c0.x * 8 + d8]);
                float2 f1 = __half22float2(hlh2[(size_t)c0.y * 8 + d8]);
                float2 f2 = __half22float2(hlh2[(size_t)c0.z * 8 + d8]);
                float2 f3 = __half22float2(hlh2[(size_t)c0.w * 8 + d8]);
                float2 f4 = __half22float2(hlh2[(size_t)c1.x * 8 + d8]);
                float2 f5 = __half22float2(hlh2[(size_t)c1.y * 8 + d8]);
                float2 f6 = __half22float2(hlh2[(size_t)c1.z * 8 + d8]);
                float2 f7 = __half22float2(hlh2[(size_t)c1.w * 8 + d8]);
                accx += ((f0.x + f1.x) + (f2.x + f3.x)) + ((f4.x + f5.x) + (f6.x + f7.x));
                accy += ((f0.y + f1.y) + (f2.y + f3.y)) + ((f4.y + f5.y) + (f6.y + f7.y));
            }
            if (j < end) {
                int4 c0 = *(const int4*)(csr + j);
                float2 f0 = __half22float2(hlh2[(size_t)c0.x * 8 + d8]);
                float2 f1 = __half22float2(hlh2[(size_t)c0.y * 8 + d8]);
                float2 f2 = __half22float2(hlh2[(size_t)c0.z * 8 + d8]);
                float2 f3 = __half22float2(hlh2[(size_t)c0.w * 8 + d8]);
                accx += (f0.x + f1.x) + (f2.x + f3.x);
                accy += (f0.y + f1.y) + (f2.y + f3.y);
            }
            bool act = valid && (d8 < 5);
            float dvv = valid ? dinv[node] : 0.f;
            float2 bb = make_float2(0.f, 0.f);
            if (d8 < 5) bb = ((const float2*)b2)[d8];
            float vx = act ? dvv * accx + bb.x : -INFINITY;
            float vy = act ? dvv * accy + bb.y : -INFINITY;
            float m = fmaxf(vx, vy);
#pragma unroll
            for (int k = 1; k < 8; k <<= 1) m = fmaxf(m, __shfl_xor(m, k, 64));
            float ex = act ? (expf(vx - m) + expf(vy - m)) : 0.f;
#pragma unroll
            for (int k = 1; k < 8; k <<= 1) ex += __shfl_xor(ex, k, 64);
            if (act) {
                float l = m + logf(ex);
                out2[(size_t)node * 5 + d8] = make_float2(vx - l, vy - l);
            }
        }
    }
}

extern "C" void kernel_launch(void* const* d_in, const int* in_sizes, int n_in,
                              void* d_out, int out_size, void* d_ws, size_t ws_size,
                              hipStream_t stream) {
    const float* x  = (const float*)d_in[0];
    const int*   ei = (const int*)d_in[1];
    const float* W1 = (const float*)d_in[2];
    const float* b1 = (const float*)d_in[3];
    const float* W2 = (const float*)d_in[4];
    const float* b2 = (const float*)d_in[5];
    float* out = (float*)d_out;
    int*   ws  = (int*)d_ws;

    // Zero the grid-barrier counters -- stream-ordered, replayed in the captured
    // graph each iteration. Never rely on workspace initial contents (re-poison).
    hipMemsetAsync(d_ws, 0, 256, stream);
    mega<<<GRID, NTHR, 0, stream>>>(x, ei, W1, b1, W2, b2, out, ws);
    (void)in_sizes; (void)n_in; (void)out_size; (void)ws_size;
}

// Round 11
// 129.264 us; speedup vs baseline: 5.8921x; 3.1769x over previous
//
#include <hip/hip_runtime.h>
#include <hip/hip_fp16.h>
#include <math.h>

#define N_NODES  50000
#define N_EDGES  800000
#define IN_DIM   64
#define HID_DIM  64
#define N_CLS    10
#define NBUCK    196      // ceil(N_NODES/256) coarse buckets (dst >> 8)
#define PBLK     256      // partition blocks
#define PCHUNK   (N_EDGES / PBLK)   // 3125 edges per chunk (exact)
#define PBSTRIDE 3136     // padded per-block packed region (ints)
#define FCAP     8192     // k_fine LDS edge cache (32 KB; max bucket ~4.4k)
#define CSTRIDE  8192     // csr slots per bucket
#define ZROW     50000    // zero-row index for pad gathers

// inclusive wave scan (64 lanes)
__device__ __forceinline__ int wscan_incl(int v, int lane) {
#pragma unroll
    for (int k = 1; k < 64; k <<= 1) {
        int u = __shfl_up(v, k, 64);
        if (lane >= k) v += u;
    }
    return v;
}

// unpack 8 fp16 (carried in a float4) and accumulate into two float4
__device__ __forceinline__ void h8_acc(float4 raw, float4& a, float4& b) {
    union { float4 f; __half2 h[4]; } u;
    u.f = raw;
    float2 p0 = __half22float2(u.h[0]);
    float2 p1 = __half22float2(u.h[1]);
    float2 p2 = __half22float2(u.h[2]);
    float2 p3 = __half22float2(u.h[3]);
    a.x += p0.x; a.y += p0.y; a.z += p1.x; a.w += p1.y;
    b.x += p2.x; b.y += p2.y; b.z += p3.x; b.w += p3.y;
}

// ---------------- pass 1: block-local counting sort by coarse bucket ----------------
// Zero global atomics; packed stream-out coalesced; pk[(block,bucket)] descriptor.
// Block 0 also zeroes the ZROW pad rows (consumed only by later gather dispatches).
__global__ __launch_bounds__(256) void k_part1(const int* __restrict__ src,
                                               const int* __restrict__ dst,
                                               int* __restrict__ pk,
                                               int* __restrict__ packedB,
                                               float2* __restrict__ xlh,
                                               __half2* __restrict__ hlh2) {
    __shared__ int hist[256];
    __shared__ int cur[256];
    __shared__ int wpart[8];
    __shared__ int dcache[PCHUNK];   // 12.5 KB
    __shared__ int sstage[PCHUNK];   // 12.5 KB
    int t = threadIdx.x;
    int lane = t & 63, w = t >> 6;
    hist[t] = 0;
    if (blockIdx.x == 0) {
        if (t < 16) xlh[(size_t)ZROW * 16 + t] = make_float2(0.f, 0.f);
        if (t >= 16 && t < 24) hlh2[(size_t)ZROW * 8 + (t - 16)] = __floats2half2_rn(0.f, 0.f);
    }
    __syncthreads();
    int beg = blockIdx.x * PCHUNK;
    for (int i = t; i < PCHUNK; i += 256) {
        int d = dst[beg + i];
        dcache[i] = d;
        atomicAdd(&hist[d >> 8], 1);          // LDS atomic
    }
    __syncthreads();
    int hv = hist[t];
    int inc = wscan_incl(hv, lane);
    if (lane == 63) wpart[w] = inc;
    __syncthreads();
    if (t < 64) { int p = (t < 4) ? wpart[t] : 0; int pi = wscan_incl(p, t); if (t < 4) wpart[t] = pi; }
    __syncthreads();
    int base = inc - hv + ((w > 0) ? wpart[w - 1] : 0);   // exclusive scan
    cur[t] = base;
    if (t < NBUCK) pk[blockIdx.x * NBUCK + t] = (base << 16) | hv;  // descriptor
    __syncthreads();
    for (int i = t; i < PCHUNK; i += 256) {
        int d = dcache[i];
        int sv = src[beg + i];
        int slot = atomicAdd(&cur[d >> 8], 1);            // LDS atomic
        sstage[slot] = ((d & 255) << 16) | sv;
    }
    __syncthreads();
    int obase = blockIdx.x * PBSTRIDE;
    for (int i = t; i < PCHUNK; i += 256)                 // coalesced stream-out
        packedB[obase + i] = sstage[i];
}

// ---------------- pass 2: per-bucket fine CSR (padded to x4) + off/nend + dinv ----------------
__global__ __launch_bounds__(512) void k_fine(const int* __restrict__ pk,
                                              const int* __restrict__ packedB,
                                              int* __restrict__ off,
                                              int* __restrict__ nend,
                                              float* __restrict__ dinv,
                                              int* __restrict__ csr) {
    __shared__ int hist[256];
    __shared__ int sA[256];      // seg begin, later csr region start per node
    __shared__ int sB[256];      // seg len
    __shared__ int sC[256];      // seg offset in ecache
    __shared__ int sc[256];      // csr cursor per node
    __shared__ int wpart[8];
    __shared__ int ecache[FCAP]; // 32 KB
    int t = threadIdx.x;
    int lane = t & 63, w = t >> 6;
    int bucket = blockIdx.x;
    if (t < 256) {
        hist[t] = 0;
        int pkv = pk[t * NBUCK + bucket];    // source block t's segment for this bucket
        sA[t] = t * PBSTRIDE + (pkv >> 16);
        sB[t] = pkv & 0xFFFF;
    }
    __syncthreads();
    // 256-entry exclusive scan of segment lengths -> ecache offsets
    int sl = (t < 256) ? sB[t] : 0;
    int inc = 0;
    if (t < 256) {
        inc = wscan_incl(sl, lane);
        if (lane == 63) wpart[w] = inc;      // w in 0..3
    }
    __syncthreads();
    if (t < 64) { int p = (t < 4) ? wpart[t] : 0; int pi = wscan_incl(p, t); if (t < 4) wpart[t] = pi; }
    __syncthreads();
    if (t < 256) sC[t] = inc - sl + ((w > 0) ? wpart[w - 1] : 0);
    __syncthreads();
    int ne = sC[255] + sB[255];
    // ingest: 2 threads per source-block segment -> ecache + per-node histogram
    {
        int bseg = t >> 1, half = t & 1;
        int sb = sA[bseg], so = sC[bseg], ln = sB[bseg];
        for (int i = half; i < ln; i += 2) {
            int p = packedB[sb + i];
            ecache[so + i] = p;
            atomicAdd(&hist[p >> 16], 1);    // LDS atomic
        }
    }
    __syncthreads();
    // padded per-node counts + scan -> csr offsets
    int hv = (t < 256) ? hist[t] : 0;
    int padded = (hv + 3) & ~3;
    if (t < 256) {
        inc = wscan_incl(padded, lane);
        if (lane == 63) wpart[w] = inc;
    }
    __syncthreads();
    if (t < 64) { int p = (t < 4) ? wpart[t] : 0; int pi = wscan_incl(p, t); if (t < 4) wpart[t] = pi; }
    __syncthreads();
    if (t < 256) {
        int o = bucket * CSTRIDE + inc - padded + ((w > 0) ? wpart[w - 1] : 0);
        sA[t] = o;                           // segments consumed; reuse as csr start
        sc[t] = o;                           // cursor
        int node = bucket * 256 + t;
        if (node < N_NODES) {
            off[node]  = o;
            nend[node] = o + padded;
            dinv[node] = rsqrtf((float)(hv + 1));   // +1 self-loop
        }
    }
    __syncthreads();
    // csr scatter via LDS cursor
    for (int i = t; i < ne; i += 512) {
        int p = ecache[i];
        int slot = atomicAdd(&sc[p >> 16], 1);
        csr[slot] = p & 0xFFFF;
    }
    __syncthreads();
    // pad fill (<=3 per node)
    if (t < 256) {
        int e2 = sA[t] + padded;
        for (int i = sc[t]; i < e2; ++i) csr[i] = ZROW;
    }
}

// ---------------- xl' = fp16((x @ W1) * dinv[row]) — 16-row tile, all-LDS inner loop ----------------
__global__ __launch_bounds__(256) void k_xw64(const float* __restrict__ x,
                                              const float* __restrict__ W,
                                              const float* __restrict__ dinv,
                                              float2* __restrict__ out /* fp16x4 */) {
    __shared__ float4 sW4[IN_DIM * 16];   // W1: 64 rows x 16 col-quads (16 KB)
    __shared__ float4 sx4[16 * 16];       // x tile: 16 rows x 16 k-quads (4 KB)
    int tid = threadIdx.x;
    const float4* W4 = (const float4*)W;
#pragma unroll
    for (int i = 0; i < 4; ++i) sW4[tid + 256 * i] = W4[tid + 256 * i];
    int rowbase = blockIdx.x * 16;
    sx4[tid] = ((const float4*)(x + (size_t)rowbase * IN_DIM))[tid];  // coalesced
    __syncthreads();
    int r  = tid >> 4;     // row in tile
    int cq = tid & 15;     // col quad
    const float4* sxr = &sx4[r * 16];
    float ax = 0.0f, ay = 0.0f, az = 0.0f, aw = 0.0f;
#pragma unroll
    for (int k4 = 0; k4 < 16; ++k4) {
        float4 xv = sxr[k4];
        float4 w0 = sW4[(k4 * 4 + 0) * 16 + cq];
        float4 w1 = sW4[(k4 * 4 + 1) * 16 + cq];
        float4 w2 = sW4[(k4 * 4 + 2) * 16 + cq];
        float4 w3 = sW4[(k4 * 4 + 3) * 16 + cq];
        ax += xv.x * w0.x + xv.y * w1.x + xv.z * w2.x + xv.w * w3.x;
        ay += xv.x * w0.y + xv.y * w1.y + xv.z * w2.y + xv.w * w3.y;
        az += xv.x * w0.z + xv.y * w1.z + xv.z * w2.z + xv.w * w3.z;
        aw += xv.x * w0.w + xv.y * w1.w + xv.z * w2.w + xv.w * w3.w;
    }
    int row = rowbase + r;
    float dv = dinv[row];
    union { __half2 h[2]; float2 f; } u;
    u.h[0] = __floats2half2_rn(ax * dv, ay * dv);
    u.h[1] = __floats2half2_rn(az * dv, aw * dv);
    out[(size_t)row * 16 + cq] = u.f;
}

// ---------------- fused layer-1 gather + relu + (h@W2)*dinv -> fp16 hl' (stride 8 half2) ----
// 8 lanes/node, float4 (fp16x8) gathers: half the VMEM instructions of the 16-lane float2 form.
__global__ __launch_bounds__(256) void k_gather64(const float4* __restrict__ xlph,
                                                  const int* __restrict__ csr,
                                                  const int* __restrict__ off,
                                                  const int* __restrict__ nend,
                                                  const float* __restrict__ dinv,
                                                  const float* __restrict__ b1,
                                                  const float* __restrict__ W2,
                                                  __half2* __restrict__ hlh2) {
    __shared__ float sW2[HID_DIM][N_CLS + 1];
    int tid = threadIdx.x;
    for (int i = tid; i < HID_DIM * N_CLS; i += 256)
        sW2[i / N_CLS][i - (i / N_CLS) * N_CLS] = W2[i];
    __syncthreads();
    int node = blockIdx.x * 32 + (tid >> 3);   // 1568*32 = 50176 >= 50000
    int d8 = tid & 7;
    bool valid = node < N_NODES;
    int nd = valid ? node : ZROW;
    int beg = 0, end = 0;
    if (valid) { beg = off[node]; end = nend[node]; }
    float4 aA = make_float4(0.f, 0.f, 0.f, 0.f);
    float4 aB = make_float4(0.f, 0.f, 0.f, 0.f);
    h8_acc(xlph[(size_t)nd * 8 + d8], aA, aB);   // self-loop (dinv[src] folded in)
    int j = beg;
    for (; j + 8 <= end; j += 8) {
        int4 c0 = *(const int4*)(csr + j);
        int4 c1 = *(const int4*)(csr + j + 4);
        float4 r0 = xlph[(size_t)c0.x * 8 + d8];
        float4 r1 = xlph[(size_t)c0.y * 8 + d8];
        float4 r2 = xlph[(size_t)c0.z * 8 + d8];
        float4 r3 = xlph[(size_t)c0.w * 8 + d8];
        float4 r4 = xlph[(size_t)c1.x * 8 + d8];
        float4 r5 = xlph[(size_t)c1.y * 8 + d8];
        float4 r6 = xlph[(size_t)c1.z * 8 + d8];
        float4 r7 = xlph[(size_t)c1.w * 8 + d8];
        h8_acc(r0, aA, aB); h8_acc(r1, aA, aB);
        h8_acc(r2, aA, aB); h8_acc(r3, aA, aB);
        h8_acc(r4, aA, aB); h8_acc(r5, aA, aB);
        h8_acc(r6, aA, aB); h8_acc(r7, aA, aB);
    }
    if (j < end) {                               // exactly one padded 4-block
        int4 c0 = *(const int4*)(csr + j);
        float4 r0 = xlph[(size_t)c0.x * 8 + d8];
        float4 r1 = xlph[(size_t)c0.y * 8 + d8];
        float4 r2 = xlph[(size_t)c0.z * 8 + d8];
        float4 r3 = xlph[(size_t)c0.w * 8 + d8];
        h8_acc(r0, aA, aB); h8_acc(r1, aA, aB);
        h8_acc(r2, aA, aB); h8_acc(r3, aA, aB);
    }
    float dv = valid ? dinv[node] : 0.0f;
    float4 b1a = ((const float4*)b1)[d8 * 2];
    float4 b1b = ((const float4*)b1)[d8 * 2 + 1];
    float h0 = fmaxf(dv * aA.x + b1a.x, 0.0f);
    float h1 = fmaxf(dv * aA.y + b1a.y, 0.0f);
    float h2 = fmaxf(dv * aA.z + b1a.z, 0.0f);
    float h3 = fmaxf(dv * aA.w + b1a.w, 0.0f);
    float h4 = fmaxf(dv * aB.x + b1b.x, 0.0f);
    float h5 = fmaxf(dv * aB.y + b1b.y, 0.0f);
    float h6 = fmaxf(dv * aB.z + b1b.z, 0.0f);
    float h7 = fmaxf(dv * aB.w + b1b.w, 0.0f);
    float p[N_CLS];
    int k0 = d8 * 8;
#pragma unroll
    for (int c = 0; c < N_CLS; ++c)
        p[c] = h0 * sW2[k0 + 0][c] + h1 * sW2[k0 + 1][c]
             + h2 * sW2[k0 + 2][c] + h3 * sW2[k0 + 3][c]
             + h4 * sW2[k0 + 4][c] + h5 * sW2[k0 + 5][c]
             + h6 * sW2[k0 + 6][c] + h7 * sW2[k0 + 7][c];
#pragma unroll
    for (int k = 1; k < 8; k <<= 1) {
#pragma unroll
        for (int c = 0; c < N_CLS; ++c) p[c] += __shfl_xor(p[c], k, 64);
    }
    if (valid) {
        float va = 0.f, vb = 0.f;
        int c0i = d8 * 2, c1i = d8 * 2 + 1;
#pragma unroll
        for (int c = 0; c < N_CLS; ++c) {
            va = (c0i == c) ? p[c] : va;
            vb = (c1i == c) ? p[c] : vb;
        }
        hlh2[(size_t)node * 8 + d8] = __floats2half2_rn(va * dv, vb * dv);  // cls 10..15 = 0
    }
}

// ---------------- layer-2 gather (fp16 hl, stride 8 half2) + b2 + log_softmax, 8 lanes/node ----
__global__ __launch_bounds__(256) void k_gather10(const __half2* __restrict__ hlh2,
                                                  const int* __restrict__ csr,
                                                  const int* __restrict__ off,
                                                  const int* __restrict__ nend,
                                                  const float* __restrict__ dinv,
                                                  const float* __restrict__ b2,
                                                  float2* __restrict__ out2) {
    int t = threadIdx.x;
    int node = blockIdx.x * 32 + (t >> 3);     // 1568*32 = 50176 >= 50000
    int d8 = t & 7;
    bool valid = node < N_NODES;
    int nd = valid ? node : ZROW;
    int beg = 0, end = 0;
    if (valid) { beg = off[node]; end = nend[node]; }
    float2 self = __half22float2(hlh2[(size_t)nd * 8 + d8]);
    float accx = self.x, accy = self.y;
    int j = beg;
    for (; j + 8 <= end; j += 8) {
        int4 c0 = *(const int4*)(csr + j);
        int4 c1 = *(const int4*)(csr + j + 4);
        float2 f0 = __half22float2(hlh2[(size_t)c0.x * 8 + d8]);
        float2 f1 = __half22float2(hlh2[(size_t)c0.y * 8 + d8]);
        float2 f2 = __half22float2(hlh2[(size_t)c0.z * 8 + d8]);
        float2 f3 = __half22float2(hlh2[(size_t)c0.w * 8 + d8]);
        float2 f4 = __half22float2(hlh2[(size_t)c1.x * 8 + d8]);
        float2 f5 = __half22float2(hlh2[(size_t)c1.y * 8 + d8]);
        float2 f6 = __half22float2(hlh2[(size_t)c1.z * 8 + d8]);
        float2 f7 = __half22float2(hlh2[(size_t)c1.w * 8 + d8]);
        accx += ((f0.x + f1.x) + (f2.x + f3.x)) + ((f4.x + f5.x) + (f6.x + f7.x));
        accy += ((f0.y + f1.y) + (f2.y + f3.y)) + ((f4.y + f5.y) + (f6.y + f7.y));
    }
    if (j < end) {
        int4 c0 = *(const int4*)(csr + j);
        float2 f0 = __half22float2(hlh2[(size_t)c0.x * 8 + d8]);
        float2 f1 = __half22float2(hlh2[(size_t)c0.y * 8 + d8]);
        float2 f2 = __half22float2(hlh2[(size_t)c0.z * 8 + d8]);
        float2 f3 = __half22float2(hlh2[(size_t)c0.w * 8 + d8]);
        accx += (f0.x + f1.x) + (f2.x + f3.x);
        accy += (f0.y + f1.y) + (f2.y + f3.y);
    }
    bool act = valid && (d8 < 5);
    float dv = valid ? dinv[node] : 0.f;
    float2 bb = make_float2(0.f, 0.f);
    if (d8 < 5) bb = ((const float2*)b2)[d8];
    float vx = act ? dv * accx + bb.x : -INFINITY;
    float vy = act ? dv * accy + bb.y : -INFINITY;
    float m = fmaxf(vx, vy);
#pragma unroll
    for (int k = 1; k < 8; k <<= 1) m = fmaxf(m, __shfl_xor(m, k, 64));
    float ex = act ? (expf(vx - m) + expf(vy - m)) : 0.f;
#pragma unroll
    for (int k = 1; k < 8; k <<= 1) ex += __shfl_xor(ex, k, 64);
    if (act) {
        float l = m + logf(ex);
        out2[(size_t)node * 5 + d8] = make_float2(vx - l, vy - l);
    }
}

extern "C" void kernel_launch(void* const* d_in, const int* in_sizes, int n_in,
                              void* d_out, int out_size, void* d_ws, size_t ws_size,
                              hipStream_t stream) {
    const float* x  = (const float*)d_in[0];
    const int*   ei = (const int*)d_in[1];
    const float* W1 = (const float*)d_in[2];
    const float* b1 = (const float*)d_in[3];
    const float* W2 = (const float*)d_in[4];
    const float* b2 = (const float*)d_in[5];
    float* out = (float*)d_out;

    const int* src = ei;             // edge_index[0]
    const int* dst = ei + N_EDGES;   // edge_index[1]

    // workspace layout (all segment starts 16B-aligned); no reliance on initial contents
    int*    pk      = (int*)d_ws;                    // 256*196 = 50176
    int*    off     = pk + 50176;                    // 50176
    int*    nend    = off + 50176;                   // 50176
    float*  dinv    = (float*)(nend + 50176);        // 50176
    int*    packedB = (int*)(dinv + 50176);          // 256*3136 = 802816 (3.2 MB)
    int*    csr     = packedB + PBLK * PBSTRIDE;     // 196*8192 = 1605632 (6.4 MB)
    float2* xlh     = (float2*)(csr + NBUCK * CSTRIDE);              // (N+1) x 16 float2
    __half2* hlh2   = (__half2*)(xlh + (size_t)(N_NODES + 1) * 16);  // (N+1) x 8 half2

    k_part1   <<<PBLK, 256, 0, stream>>>(src, dst, pk, packedB, xlh, hlh2);
    k_fine    <<<NBUCK, 512, 0, stream>>>(pk, packedB, off, nend, dinv, csr);
    k_xw64    <<<N_NODES / 16, 256, 0, stream>>>(x, W1, dinv, xlh);
    k_gather64<<<1568, 256, 0, stream>>>((const float4*)xlh, csr, off, nend, dinv, b1, W2, hlh2);
    k_gather10<<<1568, 256, 0, stream>>>(hlh2, csr, off, nend, dinv, b2, (float2*)out);
    (void)in_sizes; (void)n_in; (void)out_size; (void)ws_size;
}

// Round 12
// 122.961 us; speedup vs baseline: 6.1941x; 1.0513x over previous
//
#include <hip/hip_runtime.h>
#include <hip/hip_fp16.h>
#include <math.h>

#define N_NODES  50000
#define N_EDGES  800000
#define IN_DIM   64
#define HID_DIM  64
#define N_CLS    10
#define NBUCK    196      // ceil(N_NODES/256) coarse buckets (dst >> 8)
#define PBLK     256      // partition blocks
#define PCHUNK   (N_EDGES / PBLK)   // 3125 edges per chunk (exact)
#define PBSTRIDE 3136     // padded per-block packed region (ints)
#define FCAP     8192     // fine LDS edge cache (32 KB; max bucket ~4.4k)
#define CSTRIDE  8192     // csr slots per bucket
#define ZROW     50000    // zero-row index for pad gathers
#define XWBLK    1563     // GEMM blocks in merged dispatch: 1563*32 = 50016 rows

// inclusive wave scan (64 lanes)
__device__ __forceinline__ int wscan_incl(int v, int lane) {
#pragma unroll
    for (int k = 1; k < 64; k <<= 1) {
        int u = __shfl_up(v, k, 64);
        if (lane >= k) v += u;
    }
    return v;
}

// unpack 8 fp16 (float4 carrier), scale by s, accumulate into two float4
__device__ __forceinline__ void h8_fma(float4 raw, float s, float4& a, float4& b) {
    union { float4 f; __half2 h[4]; } u;
    u.f = raw;
    float2 p0 = __half22float2(u.h[0]);
    float2 p1 = __half22float2(u.h[1]);
    float2 p2 = __half22float2(u.h[2]);
    float2 p3 = __half22float2(u.h[3]);
    a.x += s * p0.x; a.y += s * p0.y; a.z += s * p1.x; a.w += s * p1.y;
    b.x += s * p2.x; b.y += s * p2.y; b.z += s * p3.x; b.w += s * p3.y;
}

// ---------------- pass 1: block-local counting sort by coarse bucket ----------------
// Zero global atomics; packed stream-out coalesced; pk[(block,bucket)] descriptor.
// Block 0 also zeroes the ZROW pad rows (consumed only by later dispatches).
__global__ __launch_bounds__(256) void k_part1(const int* __restrict__ src,
                                               const int* __restrict__ dst,
                                               int* __restrict__ pk,
                                               int* __restrict__ packedB,
                                               float2* __restrict__ xlh,
                                               __half2* __restrict__ hlh2) {
    __shared__ int hist[256];
    __shared__ int cur[256];
    __shared__ int wpart[8];
    __shared__ int dcache[PCHUNK];   // 12.5 KB
    __shared__ int sstage[PCHUNK];   // 12.5 KB
    int t = threadIdx.x;
    int lane = t & 63, w = t >> 6;
    hist[t] = 0;
    if (blockIdx.x == 0) {
        if (t < 16) xlh[(size_t)ZROW * 16 + t] = make_float2(0.f, 0.f);
        if (t >= 16 && t < 24) hlh2[(size_t)ZROW * 8 + (t - 16)] = __floats2half2_rn(0.f, 0.f);
    }
    __syncthreads();
    int beg = blockIdx.x * PCHUNK;
    for (int i = t; i < PCHUNK; i += 256) {
        int d = dst[beg + i];
        dcache[i] = d;
        atomicAdd(&hist[d >> 8], 1);          // LDS atomic
    }
    __syncthreads();
    int hv = hist[t];
    int inc = wscan_incl(hv, lane);
    if (lane == 63) wpart[w] = inc;
    __syncthreads();
    if (t < 64) { int p = (t < 4) ? wpart[t] : 0; int pi = wscan_incl(p, t); if (t < 4) wpart[t] = pi; }
    __syncthreads();
    int base = inc - hv + ((w > 0) ? wpart[w - 1] : 0);   // exclusive scan
    cur[t] = base;
    if (t < NBUCK) pk[blockIdx.x * NBUCK + t] = (base << 16) | hv;  // descriptor
    __syncthreads();
    for (int i = t; i < PCHUNK; i += 256) {
        int d = dcache[i];
        int sv = src[beg + i];
        int slot = atomicAdd(&cur[d >> 8], 1);            // LDS atomic
        sstage[slot] = ((d & 255) << 16) | sv;
    }
    __syncthreads();
    int obase = blockIdx.x * PBSTRIDE;
    for (int i = t; i < PCHUNK; i += 256)                 // coalesced stream-out
        packedB[obase + i] = sstage[i];
}

// ---------------- pass 2 (merged): per-bucket CSR (blocks 0..195)  ∥  X@W1 GEMM (blocks 196..) ----
// Independent halves: fine writes csr/off/nend/dinv; xw writes UNSCALED fp16 xl rows.
// dinv[src] scaling moved to the gather (per-neighbor fetch) -> no dependency, no barrier.
__global__ __launch_bounds__(512) void k_fine_xw(const int* __restrict__ pk,
                                                 const int* __restrict__ packedB,
                                                 const float* __restrict__ x,
                                                 const float* __restrict__ W1,
                                                 int* __restrict__ off,
                                                 int* __restrict__ nend,
                                                 float* __restrict__ dinv,
                                                 int* __restrict__ csr,
                                                 float2* __restrict__ xlh) {
    __shared__ __align__(16) int smem[9480];   // union: fine 37.9 KB / xw 24 KB
    int t = threadIdx.x;
    int b = blockIdx.x;
    int lane = t & 63, w = t >> 6;

    if (b < NBUCK) {
        // ---------------- fine: per-bucket CSR + off/nend/dinv ----------------
        int* hist   = smem;          // 256
        int* sA     = smem + 256;    // 256 seg begin, later csr region start
        int* sB     = smem + 512;    // 256 seg len
        int* sC     = smem + 768;    // 256 seg offset in ecache
        int* sc     = smem + 1024;   // 256 csr cursor per node
        int* wpart  = smem + 1280;   // 8
        int* ecache = smem + 1288;   // 8192
        int bucket = b;
        if (t < 256) {
            hist[t] = 0;
            int pkv = pk[t * NBUCK + bucket];
            sA[t] = t * PBSTRIDE + (pkv >> 16);
            sB[t] = pkv & 0xFFFF;
        }
        __syncthreads();
        int sl = (t < 256) ? sB[t] : 0;
        int inc = 0;
        if (t < 256) {
            inc = wscan_incl(sl, lane);
            if (lane == 63) wpart[w] = inc;      // w in 0..3
        }
        __syncthreads();
        if (t < 64) { int p = (t < 4) ? wpart[t] : 0; int pi = wscan_incl(p, t); if (t < 4) wpart[t] = pi; }
        __syncthreads();
        if (t < 256) sC[t] = inc - sl + ((w > 0) ? wpart[w - 1] : 0);
        __syncthreads();
        int ne = sC[255] + sB[255];
        {   // ingest: 2 threads per source-block segment -> ecache + node histogram
            int bseg = t >> 1, half = t & 1;
            int sb = sA[bseg], so = sC[bseg], ln = sB[bseg];
            for (int i = half; i < ln; i += 2) {
                int p = packedB[sb + i];
                ecache[so + i] = p;
                atomicAdd(&hist[p >> 16], 1);    // LDS atomic
            }
        }
        __syncthreads();
        int hv = (t < 256) ? hist[t] : 0;
        int padded = (hv + 3) & ~3;
        if (t < 256) {
            inc = wscan_incl(padded, lane);
            if (lane == 63) wpart[w] = inc;
        }
        __syncthreads();
        if (t < 64) { int p = (t < 4) ? wpart[t] : 0; int pi = wscan_incl(p, t); if (t < 4) wpart[t] = pi; }
        __syncthreads();
        if (t < 256) {
            int o = bucket * CSTRIDE + inc - padded + ((w > 0) ? wpart[w - 1] : 0);
            sA[t] = o;                           // segments consumed; reuse as csr start
            sc[t] = o;
            int node = bucket * 256 + t;
            if (node < N_NODES) {
                off[node]  = o;
                nend[node] = o + padded;
                dinv[node] = rsqrtf((float)(hv + 1));   // +1 self-loop
            } else if (node == ZROW) {
                dinv[node] = 0.0f;               // pad rows contribute exactly 0
            }
        }
        __syncthreads();
        for (int i = t; i < ne; i += 512) {      // csr scatter via LDS cursor
            int p = ecache[i];
            int slot = atomicAdd(&sc[p >> 16], 1);
            csr[slot] = p & 0xFFFF;
        }
        __syncthreads();
        if (t < 256) {                           // pad fill (<=3 per node)
            int e2 = sA[t] + padded;
            for (int i = sc[t]; i < e2; ++i) csr[i] = ZROW;
        }
    } else {
        // ---------------- xw: xl (UNSCALED) = fp16(x @ W1), 32-row tiles ----------------
        float4* sW4 = (float4*)smem;             // 1024 f4 = 16 KB
        float4* sx4 = (float4*)(smem + 4096);    // 512 f4 = 8 KB
        const float4* W4 = (const float4*)W1;
        sW4[t]       = W4[t];
        sW4[t + 512] = W4[t + 512];
        const float4* x4 = (const float4*)x;
        int r = t >> 4, cq = t & 15;
        int row0 = (b - NBUCK) * 32 + r;
        sx4[t] = (row0 < N_NODES) ? x4[(size_t)row0 * 16 + cq]
                                  : make_float4(0.f, 0.f, 0.f, 0.f);
        __syncthreads();
        const float4* sxr = &sx4[r * 16];
        float ax = 0.f, ay = 0.f, az = 0.f, aw = 0.f;
#pragma unroll
        for (int k4 = 0; k4 < 16; ++k4) {
            float4 xv = sxr[k4];
            float4 w0 = sW4[(k4 * 4 + 0) * 16 + cq];
            float4 w1 = sW4[(k4 * 4 + 1) * 16 + cq];
            float4 w2 = sW4[(k4 * 4 + 2) * 16 + cq];
            float4 w3 = sW4[(k4 * 4 + 3) * 16 + cq];
            ax += xv.x * w0.x + xv.y * w1.x + xv.z * w2.x + xv.w * w3.x;
            ay += xv.x * w0.y + xv.y * w1.y + xv.z * w2.y + xv.w * w3.y;
            az += xv.x * w0.z + xv.y * w1.z + xv.z * w2.z + xv.w * w3.z;
            aw += xv.x * w0.w + xv.y * w1.w + xv.z * w2.w + xv.w * w3.w;
        }
        if (row0 < N_NODES) {
            union { __half2 h[2]; float2 f; } u;
            u.h[0] = __floats2half2_rn(ax, ay);
            u.h[1] = __floats2half2_rn(az, aw);
            xlh[(size_t)row0 * 16 + cq] = u.f;
        }
    }
}

// ---------------- fused layer-1 gather + relu + (h@W2)*dinv -> fp16 hl' (stride 8 half2) ----
// 8 lanes/node, float4 (fp16x8) gathers; per-neighbor dinv[c] fetched (L2-resident 200 KB).
__global__ __launch_bounds__(256) void k_gather64(const float4* __restrict__ xlph,
                                                  const int* __restrict__ csr,
                                                  const int* __restrict__ off,
                                                  const int* __restrict__ nend,
                                                  const float* __restrict__ dinv,
                                                  const float* __restrict__ b1,
                                                  const float* __restrict__ W2,
                                                  __half2* __restrict__ hlh2) {
    __shared__ float sW2[HID_DIM][N_CLS + 1];
    int tid = threadIdx.x;
    for (int i = tid; i < HID_DIM * N_CLS; i += 256)
        sW2[i / N_CLS][i - (i / N_CLS) * N_CLS] = W2[i];
    __syncthreads();
    int node = blockIdx.x * 32 + (tid >> 3);   // 1568*32 = 50176 >= 50000
    int d8 = tid & 7;
    bool valid = node < N_NODES;
    int nd = valid ? node : ZROW;
    int beg = 0, end = 0;
    if (valid) { beg = off[node]; end = nend[node]; }
    float dv = valid ? dinv[node] : 0.0f;
    float4 aA = make_float4(0.f, 0.f, 0.f, 0.f);
    float4 aB = make_float4(0.f, 0.f, 0.f, 0.f);
    h8_fma(xlph[(size_t)nd * 8 + d8], dv, aA, aB);   // self-loop: dinv[n]*xl[n]
    int j = beg;
    for (; j + 8 <= end; j += 8) {
        int4 c0 = *(const int4*)(csr + j);
        int4 c1 = *(const int4*)(csr + j + 4);
        float s0 = dinv[c0.x], s1 = dinv[c0.y], s2 = dinv[c0.z], s3 = dinv[c0.w];
        float s4 = dinv[c1.x], s5 = dinv[c1.y], s6 = dinv[c1.z], s7 = dinv[c1.w];
        float4 r0 = xlph[(size_t)c0.x * 8 + d8];
        float4 r1 = xlph[(size_t)c0.y * 8 + d8];
        float4 r2 = xlph[(size_t)c0.z * 8 + d8];
        float4 r3 = xlph[(size_t)c0.w * 8 + d8];
        float4 r4 = xlph[(size_t)c1.x * 8 + d8];
        float4 r5 = xlph[(size_t)c1.y * 8 + d8];
        float4 r6 = xlph[(size_t)c1.z * 8 + d8];
        float4 r7 = xlph[(size_t)c1.w * 8 + d8];
        h8_fma(r0, s0, aA, aB); h8_fma(r1, s1, aA, aB);
        h8_fma(r2, s2, aA, aB); h8_fma(r3, s3, aA, aB);
        h8_fma(r4, s4, aA, aB); h8_fma(r5, s5, aA, aB);
        h8_fma(r6, s6, aA, aB); h8_fma(r7, s7, aA, aB);
    }
    if (j < end) {                               // exactly one padded 4-block
        int4 c0 = *(const int4*)(csr + j);
        float s0 = dinv[c0.x], s1 = dinv[c0.y], s2 = dinv[c0.z], s3 = dinv[c0.w];
        float4 r0 = xlph[(size_t)c0.x * 8 + d8];
        float4 r1 = xlph[(size_t)c0.y * 8 + d8];
        float4 r2 = xlph[(size_t)c0.z * 8 + d8];
        float4 r3 = xlph[(size_t)c0.w * 8 + d8];
        h8_fma(r0, s0, aA, aB); h8_fma(r1, s1, aA, aB);
        h8_fma(r2, s2, aA, aB); h8_fma(r3, s3, aA, aB);
    }
    float4 b1a = ((const float4*)b1)[d8 * 2];
    float4 b1b = ((const float4*)b1)[d8 * 2 + 1];
    float h0 = fmaxf(dv * aA.x + b1a.x, 0.0f);
    float h1 = fmaxf(dv * aA.y + b1a.y, 0.0f);
    float h2 = fmaxf(dv * aA.z + b1a.z, 0.0f);
    float h3 = fmaxf(dv * aA.w + b1a.w, 0.0f);
    float h4 = fmaxf(dv * aB.x + b1b.x, 0.0f);
    float h5 = fmaxf(dv * aB.y + b1b.y, 0.0f);
    float h6 = fmaxf(dv * aB.z + b1b.z, 0.0f);
    float h7 = fmaxf(dv * aB.w + b1b.w, 0.0f);
    float p[N_CLS];
    int k0 = d8 * 8;
#pragma unroll
    for (int c = 0; c < N_CLS; ++c)
        p[c] = h0 * sW2[k0 + 0][c] + h1 * sW2[k0 + 1][c]
             + h2 * sW2[k0 + 2][c] + h3 * sW2[k0 + 3][c]
             + h4 * sW2[k0 + 4][c] + h5 * sW2[k0 + 5][c]
             + h6 * sW2[k0 + 6][c] + h7 * sW2[k0 + 7][c];
#pragma unroll
    for (int k = 1; k < 8; k <<= 1) {
#pragma unroll
        for (int c = 0; c < N_CLS; ++c) p[c] += __shfl_xor(p[c], k, 64);
    }
    if (valid) {
        float va = 0.f, vb = 0.f;
        int c0i = d8 * 2, c1i = d8 * 2 + 1;
#pragma unroll
        for (int c = 0; c < N_CLS; ++c) {
            va = (c0i == c) ? p[c] : va;
            vb = (c1i == c) ? p[c] : vb;
        }
        hlh2[(size_t)node * 8 + d8] = __floats2half2_rn(va * dv, vb * dv);  // cls 10..15 = 0
    }
}

// ---------------- layer-2 gather (fp16 hl, stride 8 half2) + b2 + log_softmax, 8 lanes/node ----
__global__ __launch_bounds__(256) void k_gather10(const __half2* __restrict__ hlh2,
                                                  const int* __restrict__ csr,
                                                  const int* __restrict__ off,
                                                  const int* __restrict__ nend,
                                                  const float* __restrict__ dinv,
                                                  const float* __restrict__ b2,
                                                  float2* __restrict__ out2) {
    int t = threadIdx.x;
    int node = blockIdx.x * 32 + (t >> 3);     // 1568*32 = 50176 >= 50000
    int d8 = t & 7;
    bool valid = node < N_NODES;
    int nd = valid ? node : ZROW;
    int beg = 0, end = 0;
    if (valid) { beg = off[node]; end = nend[node]; }
    float2 self = __half22float2(hlh2[(size_t)nd * 8 + d8]);
    float accx = self.x, accy = self.y;
    int j = beg;
    for (; j + 8 <= end; j += 8) {
        int4 c0 = *(const int4*)(csr + j);
        int4 c1 = *(const int4*)(csr + j + 4);
        float2 f0 = __half22float2(hlh2[(size_t)c0.x * 8 + d8]);
        float2 f1 = __half22float2(hlh2[(size_t)c0.y * 8 + d8]);
        float2 f2 = __half22float2(hlh2[(size_t)c0.z * 8 + d8]);
        float2 f3 = __half22float2(hlh2[(size_t)c0.w * 8 + d8]);
        float2 f4 = __half22float2(hlh2[(size_t)c1.x * 8 + d8]);
        float2 f5 = __half22float2(hlh2[(size_t)c1.y * 8 + d8]);
        float2 f6 = __half22float2(hlh2[(size_t)c1.z * 8 + d8]);
        float2 f7 = __half22float2(hlh2[(size_t)c1.w * 8 + d8]);
        accx += ((f0.x + f1.x) + (f2.x + f3.x)) + ((f4.x + f5.x) + (f6.x + f7.x));
        accy += ((f0.y + f1.y) + (f2.y + f3.y)) + ((f4.y + f5.y) + (f6.y + f7.y));
    }
    if (j < end) {
        int4 c0 = *(const int4*)(csr + j);
        float2 f0 = __half22float2(hlh2[(size_t)c0.x * 8 + d8]);
        float2 f1 = __half22float2(hlh2[(size_t)c0.y * 8 + d8]);
        float2 f2 = __half22float2(hlh2[(size_t)c0.z * 8 + d8]);
        float2 f3 = __half22float2(hlh2[(size_t)c0.w * 8 + d8]);
        accx += (f0.x + f1.x) + (f2.x + f3.x);
        accy += (f0.y + f1.y) + (f2.y + f3.y);
    }
    bool act = valid && (d8 < 5);
    float dv = valid ? dinv[node] : 0.f;
    float2 bb = make_float2(0.f, 0.f);
    if (d8 < 5) bb = ((const float2*)b2)[d8];
    float vx = act ? dv * accx + bb.x : -INFINITY;
    float vy = act ? dv * accy + bb.y : -INFINITY;
    float m = fmaxf(vx, vy);
#pragma unroll
    for (int k = 1; k < 8; k <<= 1) m = fmaxf(m, __shfl_xor(m, k, 64));
    float ex = act ? (expf(vx - m) + expf(vy - m)) : 0.f;
#pragma unroll
    for (int k = 1; k < 8; k <<= 1) ex += __shfl_xor(ex, k, 64);
    if (act) {
        float l = m + logf(ex);
        out2[(size_t)node * 5 + d8] = make_float2(vx - l, vy - l);
    }
}

extern "C" void kernel_launch(void* const* d_in, const int* in_sizes, int n_in,
                              void* d_out, int out_size, void* d_ws, size_t ws_size,
                              hipStream_t stream) {
    const float* x  = (const float*)d_in[0];
    const int*   ei = (const int*)d_in[1];
    const float* W1 = (const float*)d_in[2];
    const float* b1 = (const float*)d_in[3];
    const float* W2 = (const float*)d_in[4];
    const float* b2 = (const float*)d_in[5];
    float* out = (float*)d_out;

    const int* src = ei;             // edge_index[0]
    const int* dst = ei + N_EDGES;   // edge_index[1]

    // workspace layout (all segment starts 16B-aligned); no reliance on initial contents
    int*    pk      = (int*)d_ws;                    // 256*196 = 50176
    int*    off     = pk + 50176;                    // 50176
    int*    nend    = off + 50176;                   // 50176
    float*  dinv    = (float*)(nend + 50176);        // 50176
    int*    packedB = (int*)(dinv + 50176);          // 256*3136 = 802816 (3.2 MB)
    int*    csr     = packedB + PBLK * PBSTRIDE;     // 196*8192 = 1605632 (6.4 MB)
    float2* xlh     = (float2*)(csr + NBUCK * CSTRIDE);              // (N+1) x 16 float2
    __half2* hlh2   = (__half2*)(xlh + (size_t)(N_NODES + 1) * 16);  // (N+1) x 8 half2

    k_part1   <<<PBLK, 256, 0, stream>>>(src, dst, pk, packedB, xlh, hlh2);
    k_fine_xw <<<NBUCK + XWBLK, 512, 0, stream>>>(pk, packedB, x, W1, off, nend, dinv, csr, xlh);
    k_gather64<<<1568, 256, 0, stream>>>((const float4*)xlh, csr, off, nend, dinv, b1, W2, hlh2);
    k_gather10<<<1568, 256, 0, stream>>>(hlh2, csr, off, nend, dinv, b2, (float2*)out);
    (void)in_sizes; (void)n_in; (void)out_size; (void)ws_size;
}